// Round 14
// baseline (381.892 us; speedup 1.0000x reference)
//
#include <hip/hip_runtime.h>
#include <cstdint>
#include <cstddef>

typedef short bf16x8 __attribute__((ext_vector_type(8)));
typedef float f32x4 __attribute__((ext_vector_type(4)));
typedef unsigned short u16;
typedef u16 u16x8 __attribute__((ext_vector_type(8)));

#define GLD16(gptr, lptr)                                                            \
  __builtin_amdgcn_global_load_lds((const __attribute__((address_space(1))) void*)(gptr), \
                                   (__attribute__((address_space(3))) void*)(lptr), 16, 0, 0)

__device__ __forceinline__ u16 f2bf(float f) {
  union { float f; unsigned u; } v; v.f = f;
  unsigned r = v.u + 0x7FFF + ((v.u >> 16) & 1);
  return (u16)(r >> 16);
}
__device__ __forceinline__ float bf2f(u16 h) {
  union { unsigned u; float f; } v; v.u = ((unsigned)h) << 16;
  return v.f;
}

__device__ __forceinline__ f32x4 mfma16(bf16x8 a, bf16x8 b, f32x4 c) {
  return __builtin_amdgcn_mfma_f32_16x16x32_bf16(a, b, c, 0, 0, 0);
}

// read 8 contiguous bf16 from a [rows][64] bf16 LDS tile with XOR swizzle
__device__ __forceinline__ bf16x8 lds_read_sw64(const u16* base, int row, int col) {
  int byt = row * 128 + col * 2;
  byt ^= (row & 7) << 4;
  return *(const bf16x8*)((const char*)base + byt);
}

// ---------------------------------------------------------------------------
// Weight transpose + cast: out[c][r] = bf16(in[r][c]); R,C multiples of 32
// ---------------------------------------------------------------------------
__global__ __launch_bounds__(256) void transpose_cast(const float* __restrict__ in,
                                                      u16* __restrict__ out, int R, int C) {
  __shared__ float tile[32][33];
  const int tx = threadIdx.x, ty = threadIdx.y;
  const int c0 = blockIdx.x * 32, r0 = blockIdx.y * 32;
#pragma unroll
  for (int i = 0; i < 32; i += 8)
    tile[ty + i][tx] = in[(size_t)(r0 + ty + i) * C + c0 + tx];
  __syncthreads();
#pragma unroll
  for (int i = 0; i < 32; i += 8)
    out[(size_t)(c0 + ty + i) * R + r0 + tx] = f2bf(tile[tx][ty + i]);
}

// ---------------------------------------------------------------------------
// LayerNorm (D=1024): fp32 in -> bf16 out
// ---------------------------------------------------------------------------
__global__ __launch_bounds__(256) void layernorm_bf16(const float* __restrict__ X,
                                                      const float* __restrict__ g,
                                                      const float* __restrict__ be,
                                                      u16* __restrict__ out) {
  const int row = blockIdx.x, t = threadIdx.x;
  const int lane = t & 63, wave = t >> 6;
  const float* x = X + (size_t)row * 1024;
  __shared__ float part[4];
  float v[4]; float s = 0.f;
#pragma unroll
  for (int i = 0; i < 4; ++i) { v[i] = x[t + i * 256]; s += v[i]; }
#pragma unroll
  for (int o = 32; o >= 1; o >>= 1) s += __shfl_xor(s, o);
  if (lane == 0) part[wave] = s;
  __syncthreads();
  const float mu = (part[0] + part[1] + part[2] + part[3]) * (1.f / 1024.f);
  float d2 = 0.f;
#pragma unroll
  for (int i = 0; i < 4; ++i) { float d = v[i] - mu; d2 += d * d; }
#pragma unroll
  for (int o = 32; o >= 1; o >>= 1) d2 += __shfl_xor(d2, o);
  __syncthreads();
  if (lane == 0) part[wave] = d2;
  __syncthreads();
  const float var = (part[0] + part[1] + part[2] + part[3]) * (1.f / 1024.f);
  const float rstd = rsqrtf(var + 1e-5f);
#pragma unroll
  for (int i = 0; i < 4; ++i) {
    const int c = t + i * 256;
    out[(size_t)row * 1024 + c] = f2bf((v[i] - mu) * rstd * g[c] + be[c]);
  }
}

// ---------------------------------------------------------------------------
// m97-replica 128x128 bf16 MFMA GEMM (r11, measured 830 TF): single 32KB buf.
// EPI 0: bf16 out; EPI 1: f32 out = res+acc+bias; EPI 2: bf16 gelu(acc+bias)
// ---------------------------------------------------------------------------
template <int EPI>
__global__ __launch_bounds__(256, 2) void gemm_sb(const u16* __restrict__ A,
                                                  const u16* __restrict__ Bt,
                                                  const float* __restrict__ bias,
                                                  const float* __restrict__ res,
                                                  float* __restrict__ outf,
                                                  u16* __restrict__ outb,
                                                  int M, int N, int K) {
  constexpr int ABYT = 128 * 128;   // 16KB per operand
  __shared__ __attribute__((aligned(16))) char lds[2 * ABYT];  // 32KB

  const int t = threadIdx.x, lane = t & 63, wave = t >> 6;
  const int wm = wave >> 1, wn = wave & 1;
  const int l15 = lane & 15, l16 = lane >> 4;

  const int xcd = (int)blockIdx.x & 7, q = (int)blockIdx.x >> 3;
  const int j = q & 63, gq = q >> 6;
  const int g = gq * 8 + xcd;
  const int NGN = N >> 10;
  const int gm = g / NGN, gn = g % NGN;
  const int bm = (gm * 8 + (j >> 3)) * 128;
  const int bn = (gn * 8 + (j & 7)) * 128;

  const u16* aptr[4];
  const u16* bptr[4];
#pragma unroll
  for (int c = 0; c < 4; ++c) {
    int Lb = c * 4096 + t * 16;
    int x = (Lb ^ ((Lb >> 3) & 0x70)) >> 1;
    aptr[c] = A + (size_t)(bm + (x >> 6)) * K + (x & 63);
    bptr[c] = Bt + (size_t)(bn + (x >> 6)) * K + (x & 63);
  }

  auto stage = [&](int p) {
    const int ko = p * 64;
    char* ab = lds + t * 16;
    char* bb = lds + ABYT + t * 16;
#pragma unroll
    for (int c = 0; c < 4; ++c) GLD16(aptr[c] + ko, ab + c * 4096);
#pragma unroll
    for (int c = 0; c < 4; ++c) GLD16(bptr[c] + ko, bb + c * 4096);
  };

  const int co0 = l16 * 16, co1 = 64 + l16 * 16;
  f32x4 acc[4][4] = {};
  const int nkt = K >> 6;

#pragma unroll 1
  for (int kt = 0; kt < nkt; ++kt) {
    __syncthreads();
    stage(kt);
    __syncthreads();

    const char* ab = lds;
    const char* bb = lds + ABYT;
#pragma unroll
    for (int ks = 0; ks < 2; ++ks) {
      const int co = ks ? co1 : co0;
      bf16x8 a[4], b[4];
#pragma unroll
      for (int m = 0; m < 4; ++m) {
        const int r = wm * 64 + m * 16 + l15;
        a[m] = *(const bf16x8*)(ab + r * 128 + (co ^ ((r & 7) << 4)));
      }
#pragma unroll
      for (int n = 0; n < 4; ++n) {
        const int r = wn * 64 + n * 16 + l15;
        b[n] = *(const bf16x8*)(bb + r * 128 + (co ^ ((r & 7) << 4)));
      }
#pragma unroll
      for (int m = 0; m < 4; ++m)
#pragma unroll
        for (int n = 0; n < 4; ++n)
          acc[m][n] = mfma16(a[m], b[n], acc[m][n]);
    }
  }

  const int r0 = l16 * 4;
#pragma unroll
  for (int m = 0; m < 4; ++m) {
#pragma unroll
    for (int n = 0; n < 4; ++n) {
      const int col = bn + wn * 64 + n * 16 + l15;
      const float bv = bias[col];
#pragma unroll
      for (int r = 0; r < 4; ++r) {
        const int row = bm + wm * 64 + m * 16 + r0 + r;
        const float v = acc[m][n][r] + bv;
        const size_t o = (size_t)row * N + col;
        if (EPI == 0) {
          outb[o] = f2bf(v);
        } else if (EPI == 1) {
          outf[o] = res[o] + v;
        } else {
          const float u = 0.7978845608f * (v + 0.044715f * v * v * v);
          const float e = __expf(2.f * u);
          const float th = 1.f - 2.f / (1.f + e);
          outb[o] = f2bf(0.5f * v * (1.f + th));
        }
      }
    }
  }
}

// ---------------------------------------------------------------------------
// Fused attention: scores + softmax + A-accumulate + PV in ONE kernel.
// Grid (8 qblk, 32 b), 256 thr (4 waves). Block = 32 q-rows, loops 16 heads.
// Wave w: rg=w&1 (q-row group of 16), kh=w>>1 (k-half of 128 for scores;
// d-half of 32 for PV). Per head:
//   top: vmcnt(0) [K/Q gld_lds + V reg loads landed]; sync
//   A: scatter V regs -> Vs (attn_pv pattern); issue V(h+1) reg loads
//   B: scores 16 MFMA from Ks/Qs (attn_scores pattern)
//   C: softmax; cross-(k-half) max/sum via 512B LDS exchange (2 syncs)
//   D: A_acc += p (regs); write P -> Ps (swizzled); sync; issue K/Q(h+1) gld_lds
//   E: PV 16 MFMA from Ps/Vs; write ctx chunk
// A written once at end (f32, /16). No probs global traffic at all.
// LDS 84.5KB -> 1 block/CU; 256 blocks = full chip.
// ---------------------------------------------------------------------------
__global__ __launch_bounds__(256) void attn_fused(const u16* __restrict__ qkv,
                                                  u16* __restrict__ ctx,
                                                  float* __restrict__ Aout) {
  __shared__ u16 Ks[256 * 64];   // 32KB swizzled [k][d]
  __shared__ u16 Vs[64 * 256];   // 32KB swizzled [d][k]
  __shared__ u16 Qs[32 * 64];    //  4KB swizzled [q][d]
  __shared__ u16 Ps[32 * 256];   // 16KB swizzled [q][k] (512B rows)
  __shared__ float red[2][2][32];

  const int t = threadIdx.x, lane = t & 63, wave = t >> 6;
  const int rg = wave & 1, kh = wave >> 1;
  const int l15 = lane & 15, l16 = lane >> 4;
  const int q0 = blockIdx.x * 32, b = blockIdx.y;
  const size_t base = (size_t)b * 256 * 3072;

  // pre-swizzled staging indices
  int kk_s[8], kd_s[8];
#pragma unroll
  for (int is = 0; is < 8; ++is) {
    int L = (is * 2048 + t * 8) * 2;
    int x = (L ^ ((L >> 3) & 0x70)) >> 1;
    kk_s[is] = x >> 6; kd_s[is] = x & 63;
  }
  int qr_s, qd_s;
  { int L = t * 16; int x = (L ^ ((L >> 3) & 0x70)) >> 1; qr_s = x >> 6; qd_s = x & 63; }
  int vkk[8], vd0[8];
#pragma unroll
  for (int p = 0; p < 8; ++p) { int idx = p * 2048 + t * 8; vkk[p] = idx >> 6; vd0[p] = idx & 63; }

  auto stageKQ = [&](int h) {
#pragma unroll
    for (int is = 0; is < 8; ++is)
      GLD16(qkv + base + (size_t)kk_s[is] * 3072 + 1024 + h * 64 + kd_s[is],
            (char*)Ks + is * 4096 + wave * 1024);
    GLD16(qkv + base + (size_t)(q0 + qr_s) * 3072 + h * 64 + qd_s,
          (char*)Qs + wave * 1024);
  };

  // prologue: head 0 staging in flight
  u16x8 vvr[8];
  stageKQ(0);
#pragma unroll
  for (int p = 0; p < 8; ++p)
    vvr[p] = *(const u16x8*)(qkv + base + (size_t)vkk[p] * 3072 + 2048 + vd0[p]);

  f32x4 A_acc[8] = {};

#pragma unroll 1
  for (int h = 0; h < 16; ++h) {
    asm volatile("s_waitcnt vmcnt(0)" ::: "memory");
    __syncthreads();               // K/Q/V(h) ready; Vs/Ps free (all PV done)

    // Phase A: scatter V regs -> Vs; prefetch V(h+1) into regs
#pragma unroll
    for (int p = 0; p < 8; ++p) {
#pragma unroll
      for (int jj = 0; jj < 8; ++jj) {
        const int d = vd0[p] + jj;
        const int byt = (d * 512 + vkk[p] * 2) ^ ((d & 7) << 4);
        *(u16*)((char*)Vs + byt) = vvr[p][jj];
      }
    }
    if (h + 1 < 16) {
#pragma unroll
      for (int p = 0; p < 8; ++p)
        vvr[p] = *(const u16x8*)(qkv + base + (size_t)vkk[p] * 3072 + 2048 + (h + 1) * 64 + vd0[p]);
    }

    // Phase B: scores (16 rows x 128 cols per wave)
    f32x4 acc2[8] = {};
    bf16x8 aq[2];
#pragma unroll
    for (int ks = 0; ks < 2; ++ks)
      aq[ks] = lds_read_sw64(Qs, rg * 16 + l15, ks * 32 + l16 * 8);
#pragma unroll
    for (int nf = 0; nf < 8; ++nf) {
#pragma unroll
      for (int ks = 0; ks < 2; ++ks) {
        bf16x8 bk = lds_read_sw64(Ks, (kh * 8 + nf) * 16 + l15, ks * 32 + l16 * 8);
        acc2[nf] = mfma16(aq[ks], bk, acc2[nf]);
      }
    }

    // Phase C: softmax with cross-k-half exchange
    float mx[4], sm[4];
#pragma unroll
    for (int r = 0; r < 4; ++r) {
      float m = -1e30f;
#pragma unroll
      for (int nf = 0; nf < 8; ++nf) m = fmaxf(m, acc2[nf][r]);
#pragma unroll
      for (int o = 8; o >= 1; o >>= 1) m = fmaxf(m, __shfl_xor(m, o));
      mx[r] = m;
    }
    if (l15 == 0) {
#pragma unroll
      for (int r = 0; r < 4; ++r) red[0][kh][rg * 16 + l16 * 4 + r] = mx[r];
    }
    __syncthreads();
#pragma unroll
    for (int r = 0; r < 4; ++r) {
      const int qr = rg * 16 + l16 * 4 + r;
      const float gm = fmaxf(red[0][0][qr], red[0][1][qr]);
      float s = 0.f;
#pragma unroll
      for (int nf = 0; nf < 8; ++nf) {
        const float e = __expf((acc2[nf][r] - gm) * 0.125f);
        acc2[nf][r] = e; s += e;
      }
#pragma unroll
      for (int o = 8; o >= 1; o >>= 1) s += __shfl_xor(s, o);
      sm[r] = s;
    }
    if (l15 == 0) {
#pragma unroll
      for (int r = 0; r < 4; ++r) red[1][kh][rg * 16 + l16 * 4 + r] = sm[r];
    }
    __syncthreads();

    // Phase D: A_acc += p; write Ps
#pragma unroll
    for (int r = 0; r < 4; ++r) {
      const int qr = rg * 16 + l16 * 4 + r;
      const float rinv = 1.f / (red[1][0][qr] + red[1][1][qr]);
#pragma unroll
      for (int nf = 0; nf < 8; ++nf) {
        const float p = acc2[nf][r] * rinv;
        A_acc[nf][r] += p;
        const int kcol = kh * 128 + nf * 16 + l15;
        const int byt = (qr * 512 + kcol * 2) ^ ((qr & 7) << 4);
        *(u16*)((char*)Ps + byt) = f2bf(p);
      }
    }
    __syncthreads();               // Ps/Vs complete; Ks/Qs dead -> prefetch
    if (h + 1 < 16) stageKQ(h + 1);

    // Phase E: PV (16 rows x 32 d-cols per wave) + ctx write
    f32x4 cacc[2] = {};
#pragma unroll
    for (int kt = 0; kt < 8; ++kt) {
      const int prow = rg * 16 + l15;
      const int pbyt = (prow * 512 + kt * 64 + l16 * 16) ^ ((prow & 7) << 4);
      const bf16x8 a = *(const bf16x8*)((const char*)Ps + pbyt);
#pragma unroll
      for (int n = 0; n < 2; ++n) {
        const int d = kh * 32 + n * 16 + l15;
        const int kk = kt * 32 + l16 * 8;
        const int vbyt = (d * 512 + kk * 2) ^ ((d & 7) << 4);
        const bf16x8 v = *(const bf16x8*)((const char*)Vs + vbyt);
        cacc[n] = mfma16(a, v, cacc[n]);
      }
    }
#pragma unroll
    for (int n = 0; n < 2; ++n) {
      const int dcol = h * 64 + kh * 32 + n * 16 + l15;
#pragma unroll
      for (int r = 0; r < 4; ++r) {
        const int qr = rg * 16 + l16 * 4 + r;
        ctx[(size_t)(b * 256 + q0 + qr) * 1024 + dcol] = f2bf(cacc[n][r]);
      }
    }
  }

  // epilogue: A = mean over heads
#pragma unroll
  for (int nf = 0; nf < 8; ++nf) {
    const int kcol = kh * 128 + nf * 16 + l15;
#pragma unroll
    for (int r = 0; r < 4; ++r) {
      const int qr = rg * 16 + l16 * 4 + r;
      Aout[(size_t)(b * 256 + q0 + qr) * 256 + kcol] = A_acc[nf][r] * (1.f / 16.f);
    }
  }
}

// ---------------------------------------------------------------------------
extern "C" void kernel_launch(void* const* d_in, const int* in_sizes, int n_in,
                              void* d_out, int out_size, void* d_ws, size_t ws_size,
                              hipStream_t stream) {
  const float* X      = (const float*)d_in[0];
  const float* W_qkv  = (const float*)d_in[1];
  const float* b_qkv  = (const float*)d_in[2];
  const float* W_proj = (const float*)d_in[3];
  const float* b_proj = (const float*)d_in[4];
  const float* g1     = (const float*)d_in[5];
  const float* beta1  = (const float*)d_in[6];
  const float* g2     = (const float*)d_in[7];
  const float* beta2  = (const float*)d_in[8];
  const float* W_ff1  = (const float*)d_in[9];
  const float* b_ff1  = (const float*)d_in[10];
  const float* W_ff2  = (const float*)d_in[11];
  const float* b_ff2  = (const float*)d_in[12];

  float* Xout = (float*)d_out;                 // [8192][1024]
  float* Aout = (float*)d_out + 8388608;       // [32][256][256]

  char* ws = (char*)d_ws;
  const size_t MB = 1u << 20;
  u16* xn    = (u16*)(ws + 0);          // 16MB: Xn, then ctx, then X1n
  u16* wqkv  = (u16*)(ws + 16 * MB);    // 6MB [3072][1024]
  u16* wproj = (u16*)(ws + 22 * MB);    // 2MB [1024][1024]
  u16* wff1  = (u16*)(ws + 24 * MB);    // 8MB [4096][1024]
  u16* wff2  = (u16*)(ws + 32 * MB);    // 8MB [1024][4096]
  u16* qkv   = (u16*)(ws + 40 * MB);    // 48MB [8192][3072]
  u16* hbuf  = (u16*)(ws + 88 * MB);    // 64MB [8192][4096]
  float* x1  = (float*)(ws + 152 * MB); // 32MB [8192][1024]  (total 184MB)
  u16* ctx   = xn;                      // reuse region 0 after QKV GEMM
  u16* x1n   = xn;                      // reuse region 0 after proj GEMM

  const dim3 tb(32, 8);
  transpose_cast<<<dim3(96, 32),  tb, 0, stream>>>(W_qkv,  wqkv, 1024, 3072);
  transpose_cast<<<dim3(32, 32),  tb, 0, stream>>>(W_proj, wproj, 1024, 1024);
  transpose_cast<<<dim3(128, 32), tb, 0, stream>>>(W_ff1,  wff1, 1024, 4096);
  transpose_cast<<<dim3(32, 128), tb, 0, stream>>>(W_ff2,  wff2, 4096, 1024);

  layernorm_bf16<<<8192, 256, 0, stream>>>(X, g1, beta1, xn);

  // QKV: 128x128, grid 64x24 = 1536 blocks.
  gemm_sb<0><<<1536, 256, 0, stream>>>(xn, wqkv, b_qkv, nullptr, nullptr, qkv,
                                       8192, 3072, 1024);

  // Fused attention: scores+softmax+A+PV, one dispatch (256 blocks).
  attn_fused<<<dim3(8, 32), 256, 0, stream>>>(qkv, ctx, Aout);

  // proj + residual: grid 64x8 = 512 blocks.
  gemm_sb<1><<<512, 256, 0, stream>>>(ctx, wproj, b_proj, X, x1, nullptr,
                                      8192, 1024, 1024);

  layernorm_bf16<<<8192, 256, 0, stream>>>(x1, g2, beta2, x1n);

  // FF1 + GELU: grid 64x32 = 2048 blocks.
  gemm_sb<2><<<2048, 256, 0, stream>>>(x1n, wff1, b_ff1, nullptr, nullptr, hbuf,
                                       8192, 4096, 1024);

  // FF2 + residual: grid 64x8 = 512 blocks.
  gemm_sb<1><<<512, 256, 0, stream>>>(hbuf, wff2, b_ff2, x1, Xout, nullptr,
                                      8192, 1024, 4096);
}

// Round 15
// 336.317 us; speedup vs baseline: 1.1355x; 1.1355x over previous
//
#include <hip/hip_runtime.h>
#include <cstdint>
#include <cstddef>

typedef short bf16x8 __attribute__((ext_vector_type(8)));
typedef float f32x4 __attribute__((ext_vector_type(4)));
typedef unsigned short u16;
typedef u16 u16x8 __attribute__((ext_vector_type(8)));

#define GLD16(gptr, lptr)                                                            \
  __builtin_amdgcn_global_load_lds((const __attribute__((address_space(1))) void*)(gptr), \
                                   (__attribute__((address_space(3))) void*)(lptr), 16, 0, 0)

__device__ __forceinline__ u16 f2bf(float f) {
  union { float f; unsigned u; } v; v.f = f;
  unsigned r = v.u + 0x7FFF + ((v.u >> 16) & 1);
  return (u16)(r >> 16);
}
__device__ __forceinline__ float bf2f(u16 h) {
  union { unsigned u; float f; } v; v.u = ((unsigned)h) << 16;
  return v.f;
}

__device__ __forceinline__ f32x4 mfma16(bf16x8 a, bf16x8 b, f32x4 c) {
  return __builtin_amdgcn_mfma_f32_16x16x32_bf16(a, b, c, 0, 0, 0);
}

// read 8 contiguous bf16 from a [rows][64] bf16 LDS tile with XOR swizzle
__device__ __forceinline__ bf16x8 lds_read_sw64(const u16* base, int row, int col) {
  int byt = row * 128 + col * 2;
  byt ^= (row & 7) << 4;
  return *(const bf16x8*)((const char*)base + byt);
}

// ---------------------------------------------------------------------------
// Weight transpose + cast: out[c][r] = bf16(in[r][c]); R,C multiples of 32
// ---------------------------------------------------------------------------
__global__ __launch_bounds__(256) void transpose_cast(const float* __restrict__ in,
                                                      u16* __restrict__ out, int R, int C) {
  __shared__ float tile[32][33];
  const int tx = threadIdx.x, ty = threadIdx.y;
  const int c0 = blockIdx.x * 32, r0 = blockIdx.y * 32;
#pragma unroll
  for (int i = 0; i < 32; i += 8)
    tile[ty + i][tx] = in[(size_t)(r0 + ty + i) * C + c0 + tx];
  __syncthreads();
#pragma unroll
  for (int i = 0; i < 32; i += 8)
    out[(size_t)(c0 + ty + i) * R + r0 + tx] = f2bf(tile[tx][ty + i]);
}

// ---------------------------------------------------------------------------
// LayerNorm (D=1024): fp32 in -> bf16 out
// ---------------------------------------------------------------------------
__global__ __launch_bounds__(256) void layernorm_bf16(const float* __restrict__ X,
                                                      const float* __restrict__ g,
                                                      const float* __restrict__ be,
                                                      u16* __restrict__ out) {
  const int row = blockIdx.x, t = threadIdx.x;
  const int lane = t & 63, wave = t >> 6;
  const float* x = X + (size_t)row * 1024;
  __shared__ float part[4];
  float v[4]; float s = 0.f;
#pragma unroll
  for (int i = 0; i < 4; ++i) { v[i] = x[t + i * 256]; s += v[i]; }
#pragma unroll
  for (int o = 32; o >= 1; o >>= 1) s += __shfl_xor(s, o);
  if (lane == 0) part[wave] = s;
  __syncthreads();
  const float mu = (part[0] + part[1] + part[2] + part[3]) * (1.f / 1024.f);
  float d2 = 0.f;
#pragma unroll
  for (int i = 0; i < 4; ++i) { float d = v[i] - mu; d2 += d * d; }
#pragma unroll
  for (int o = 32; o >= 1; o >>= 1) d2 += __shfl_xor(d2, o);
  __syncthreads();
  if (lane == 0) part[wave] = d2;
  __syncthreads();
  const float var = (part[0] + part[1] + part[2] + part[3]) * (1.f / 1024.f);
  const float rstd = rsqrtf(var + 1e-5f);
#pragma unroll
  for (int i = 0; i < 4; ++i) {
    const int c = t + i * 256;
    out[(size_t)row * 1024 + c] = f2bf((v[i] - mu) * rstd * g[c] + be[c]);
  }
}

// ---------------------------------------------------------------------------
// m97-replica 128x128 bf16 MFMA GEMM (r11, measured ~830 TF): single 32KB
// LDS buffer, full drain per K-step, ~2.7 blocks/CU cross-block overlap.
// Used for the large-N GEMMs (QKV, FF1) where it measured fastest.
// EPI 0: bf16 out; EPI 1: f32 out = res+acc+bias; EPI 2: bf16 gelu(acc+bias)
// ---------------------------------------------------------------------------
template <int EPI>
__global__ __launch_bounds__(256, 2) void gemm_sb(const u16* __restrict__ A,
                                                  const u16* __restrict__ Bt,
                                                  const float* __restrict__ bias,
                                                  const float* __restrict__ res,
                                                  float* __restrict__ outf,
                                                  u16* __restrict__ outb,
                                                  int M, int N, int K) {
  constexpr int ABYT = 128 * 128;   // 16KB per operand
  __shared__ __attribute__((aligned(16))) char lds[2 * ABYT];  // 32KB

  const int t = threadIdx.x, lane = t & 63, wave = t >> 6;
  const int wm = wave >> 1, wn = wave & 1;
  const int l15 = lane & 15, l16 = lane >> 4;

  const int xcd = (int)blockIdx.x & 7, q = (int)blockIdx.x >> 3;
  const int j = q & 63, gq = q >> 6;
  const int g = gq * 8 + xcd;
  const int NGN = N >> 10;
  const int gm = g / NGN, gn = g % NGN;
  const int bm = (gm * 8 + (j >> 3)) * 128;
  const int bn = (gn * 8 + (j & 7)) * 128;

  const u16* aptr[4];
  const u16* bptr[4];
#pragma unroll
  for (int c = 0; c < 4; ++c) {
    int Lb = c * 4096 + t * 16;
    int x = (Lb ^ ((Lb >> 3) & 0x70)) >> 1;
    aptr[c] = A + (size_t)(bm + (x >> 6)) * K + (x & 63);
    bptr[c] = Bt + (size_t)(bn + (x >> 6)) * K + (x & 63);
  }

  auto stage = [&](int p) {
    const int ko = p * 64;
    char* ab = lds + t * 16;
    char* bb = lds + ABYT + t * 16;
#pragma unroll
    for (int c = 0; c < 4; ++c) GLD16(aptr[c] + ko, ab + c * 4096);
#pragma unroll
    for (int c = 0; c < 4; ++c) GLD16(bptr[c] + ko, bb + c * 4096);
  };

  const int co0 = l16 * 16, co1 = 64 + l16 * 16;
  f32x4 acc[4][4] = {};
  const int nkt = K >> 6;

#pragma unroll 1
  for (int kt = 0; kt < nkt; ++kt) {
    __syncthreads();
    stage(kt);
    __syncthreads();

    const char* ab = lds;
    const char* bb = lds + ABYT;
#pragma unroll
    for (int ks = 0; ks < 2; ++ks) {
      const int co = ks ? co1 : co0;
      bf16x8 a[4], b[4];
#pragma unroll
      for (int m = 0; m < 4; ++m) {
        const int r = wm * 64 + m * 16 + l15;
        a[m] = *(const bf16x8*)(ab + r * 128 + (co ^ ((r & 7) << 4)));
      }
#pragma unroll
      for (int n = 0; n < 4; ++n) {
        const int r = wn * 64 + n * 16 + l15;
        b[n] = *(const bf16x8*)(bb + r * 128 + (co ^ ((r & 7) << 4)));
      }
#pragma unroll
      for (int m = 0; m < 4; ++m)
#pragma unroll
        for (int n = 0; n < 4; ++n)
          acc[m][n] = mfma16(a[m], b[n], acc[m][n]);
    }
  }

  const int r0 = l16 * 4;
#pragma unroll
  for (int m = 0; m < 4; ++m) {
#pragma unroll
    for (int n = 0; n < 4; ++n) {
      const int col = bn + wn * 64 + n * 16 + l15;
      const float bv = bias[col];
#pragma unroll
      for (int r = 0; r < 4; ++r) {
        const int row = bm + wm * 64 + m * 16 + r0 + r;
        const float v = acc[m][n][r] + bv;
        const size_t o = (size_t)row * N + col;
        if (EPI == 0) {
          outb[o] = f2bf(v);
        } else if (EPI == 1) {
          outf[o] = res[o] + v;
        } else {
          const float u = 0.7978845608f * (v + 0.044715f * v * v * v);
          const float e = __expf(2.f * u);
          const float th = 1.f - 2.f / (1.f + e);
          outb[o] = f2bf(0.5f * v * (1.f + th));
        }
      }
    }
  }
}

// ---------------------------------------------------------------------------
// Ring-2 double-buffer 128x128 GEMM (r10): one-step prefetch slack hides the
// vmcnt drain. Used for proj and FF2 (measured faster there than gemm_sb).
// ---------------------------------------------------------------------------
template <int EPI>
__global__ __launch_bounds__(256, 2) void gemm_128(const u16* __restrict__ A,
                                                   const u16* __restrict__ Bt,
                                                   const float* __restrict__ bias,
                                                   const float* __restrict__ res,
                                                   float* __restrict__ outf,
                                                   u16* __restrict__ outb,
                                                   int M, int N, int K) {
  constexpr int ABYT = 128 * 128;   // 16KB per K-tile per operand
  __shared__ __attribute__((aligned(16))) char lds[4 * ABYT];  // 64KB

  const int t = threadIdx.x, lane = t & 63, wave = t >> 6;
  const int wm = wave >> 1, wn = wave & 1;
  const int l15 = lane & 15, l16 = lane >> 4;

  const int xcd = (int)blockIdx.x & 7, q = (int)blockIdx.x >> 3;
  const int j = q & 63, gq = q >> 6;
  const int g = gq * 8 + xcd;
  const int NGN = N >> 10;
  const int gm = g / NGN, gn = g % NGN;
  const int bm = (gm * 8 + (j >> 3)) * 128;
  const int bn = (gn * 8 + (j & 7)) * 128;

  const u16* aptr[4];
  const u16* bptr[4];
#pragma unroll
  for (int c = 0; c < 4; ++c) {
    int Lb = c * 4096 + t * 16;
    int x = (Lb ^ ((Lb >> 3) & 0x70)) >> 1;
    aptr[c] = A + (size_t)(bm + (x >> 6)) * K + (x & 63);
    bptr[c] = Bt + (size_t)(bn + (x >> 6)) * K + (x & 63);
  }

  auto stage = [&](int p) {
    const int ko = p * 64;
    const int s = p & 1;
    char* ab = lds + s * ABYT + t * 16;
    char* bb = lds + 2 * ABYT + s * ABYT + t * 16;
#pragma unroll
    for (int c = 0; c < 4; ++c) GLD16(aptr[c] + ko, ab + c * 4096);
#pragma unroll
    for (int c = 0; c < 4; ++c) GLD16(bptr[c] + ko, bb + c * 4096);
  };
  stage(0);

  const int co0 = l16 * 16, co1 = 64 + l16 * 16;
  f32x4 acc[4][4] = {};
  const int nkt = K >> 6;

#pragma unroll 1
  for (int kt = 0; kt < nkt; ++kt) {
    asm volatile("s_waitcnt vmcnt(0)" ::: "memory");
    asm volatile("s_barrier" ::: "memory");
    if (kt + 1 < nkt) stage(kt + 1);

    const int s = kt & 1;
    const char* ab = lds + s * ABYT;
    const char* bb = lds + 2 * ABYT + s * ABYT;
#pragma unroll
    for (int ks = 0; ks < 2; ++ks) {
      const int co = ks ? co1 : co0;
      bf16x8 a[4], b[4];
#pragma unroll
      for (int m = 0; m < 4; ++m) {
        const int r = wm * 64 + m * 16 + l15;
        a[m] = *(const bf16x8*)(ab + r * 128 + (co ^ ((r & 7) << 4)));
      }
#pragma unroll
      for (int n = 0; n < 4; ++n) {
        const int r = wn * 64 + n * 16 + l15;
        b[n] = *(const bf16x8*)(bb + r * 128 + (co ^ ((r & 7) << 4)));
      }
      __builtin_amdgcn_s_setprio(1);
#pragma unroll
      for (int m = 0; m < 4; ++m)
#pragma unroll
        for (int n = 0; n < 4; ++n)
          acc[m][n] = mfma16(a[m], b[n], acc[m][n]);
      __builtin_amdgcn_s_setprio(0);
    }
  }

  const int r0 = l16 * 4;
#pragma unroll
  for (int m = 0; m < 4; ++m) {
#pragma unroll
    for (int n = 0; n < 4; ++n) {
      const int col = bn + wn * 64 + n * 16 + l15;
      const float bv = bias[col];
#pragma unroll
      for (int r = 0; r < 4; ++r) {
        const int row = bm + wm * 64 + m * 16 + r0 + r;
        const float v = acc[m][n][r] + bv;
        const size_t o = (size_t)row * N + col;
        if (EPI == 0) {
          outb[o] = f2bf(v);
        } else if (EPI == 1) {
          outf[o] = res[o] + v;
        } else {
          const float u = 0.7978845608f * (v + 0.044715f * v * v * v);
          const float e = __expf(2.f * u);
          const float th = 1.f - 2.f / (1.f + e);
          outb[o] = f2bf(0.5f * v * (1.f + th));
        }
      }
    }
  }
}

// ---------------------------------------------------------------------------
// Attention scores + softmax -> probs (bf16). grid(4 qblk, 16 h, 32 b), 256 thr
// probs layout: [b][h][q][k] = [((b*16+h)*256+q)*256+k]
// ---------------------------------------------------------------------------
__global__ __launch_bounds__(256) void attn_scores(const u16* __restrict__ qkv,
                                                   u16* __restrict__ probs) {
  __shared__ u16 Ks[256 * 64];
  __shared__ u16 Qs[64 * 64];
  const int t = threadIdx.x, lane = t & 63, wave = t >> 6;
  const int qb = blockIdx.x * 64, h = blockIdx.y, b = blockIdx.z;
  const size_t row0 = (size_t)b * 256 * 3072;

#pragma unroll
  for (int is = 0; is < 8; ++is) {
    int L = (is * 2048 + t * 8) * 2;
    int x = (L ^ ((L >> 3) & 0x70)) >> 1;
    int kk = x >> 6, d = x & 63;
    const u16* gp = qkv + row0 + (size_t)kk * 3072 + 1024 + h * 64 + d;
    GLD16(gp, (char*)Ks + is * 4096 + wave * 1024);
  }
#pragma unroll
  for (int is = 0; is < 2; ++is) {
    int L = (is * 2048 + t * 8) * 2;
    int x = (L ^ ((L >> 3) & 0x70)) >> 1;
    int q = x >> 6, d = x & 63;
    const u16* gp = qkv + row0 + (size_t)(qb + q) * 3072 + h * 64 + d;
    GLD16(gp, (char*)Qs + is * 4096 + wave * 1024);
  }
  __syncthreads();

  f32x4 acc[16] = {};
  bf16x8 aq[2];
#pragma unroll
  for (int ks = 0; ks < 2; ++ks)
    aq[ks] = lds_read_sw64(Qs, wave * 16 + (lane & 15), ks * 32 + (lane >> 4) * 8);
#pragma unroll
  for (int nf = 0; nf < 16; ++nf) {
#pragma unroll
    for (int ks = 0; ks < 2; ++ks) {
      bf16x8 bk = lds_read_sw64(Ks, nf * 16 + (lane & 15), ks * 32 + (lane >> 4) * 8);
      acc[nf] = mfma16(aq[ks], bk, acc[nf]);
    }
  }

  const int r0 = (lane >> 4) * 4, cc = lane & 15;
  const float sc = 0.125f;
#pragma unroll
  for (int r = 0; r < 4; ++r) {
    float mx = -1e30f;
#pragma unroll
    for (int nf = 0; nf < 16; ++nf) mx = fmaxf(mx, acc[nf][r]);
#pragma unroll
    for (int o = 8; o >= 1; o >>= 1) mx = fmaxf(mx, __shfl_xor(mx, o));
    float s = 0.f;
#pragma unroll
    for (int nf = 0; nf < 16; ++nf) {
      float e = __expf((acc[nf][r] - mx) * sc);
      acc[nf][r] = e; s += e;
    }
#pragma unroll
    for (int o = 8; o >= 1; o >>= 1) s += __shfl_xor(s, o);
    const float rinv = 1.f / s;
    const int qrow = qb + wave * 16 + r0 + r;
    u16* prow = probs + (size_t)((b * 16 + h) * 256 + qrow) * 256;
#pragma unroll
    for (int nf = 0; nf < 16; ++nf)
      prow[nf * 16 + cc] = f2bf(acc[nf][r] * rinv);
  }
}

// ---------------------------------------------------------------------------
// A = mean over heads of probs. grid(8192=b*256+q), 256 thr
// ---------------------------------------------------------------------------
__global__ __launch_bounds__(256) void amean(const u16* __restrict__ probs,
                                             float* __restrict__ A) {
  const int bq = blockIdx.x;
  const int b = bq >> 8, q = bq & 255;
  const int t = threadIdx.x;
  float s = 0.f;
#pragma unroll
  for (int h = 0; h < 16; ++h)
    s += bf2f(probs[(size_t)((b * 16 + h) * 256 + q) * 256 + t]);
  A[(size_t)bq * 256 + t] = s * (1.f / 16.f);
}

// ---------------------------------------------------------------------------
// PV: ctx[b,:,h*64:+64] = probs[b,h] @ V[b,h]. grid(16 h, 32 b), 256 thr
// ---------------------------------------------------------------------------
__global__ __launch_bounds__(256) void attn_pv(const u16* __restrict__ qkv,
                                               const u16* __restrict__ probs,
                                               u16* __restrict__ ctx) {
  __shared__ u16 Vs[64 * 256];
  const int t = threadIdx.x, lane = t & 63, wave = t >> 6;
  const int h = blockIdx.x, b = blockIdx.y;

#pragma unroll
  for (int p = 0; p < 8; ++p) {
    int idx = p * 2048 + t * 8;
    int kk = idx >> 6, d0 = idx & 63;
    u16x8 vv = *(const u16x8*)(qkv + (size_t)(b * 256 + kk) * 3072 + 2048 + h * 64 + d0);
#pragma unroll
    for (int j = 0; j < 8; ++j) {
      int d = d0 + j;
      int byt = (d * 512 + kk * 2) ^ ((d & 7) << 4);
      *(u16*)((char*)Vs + byt) = vv[j];
    }
  }
  __syncthreads();

  f32x4 acc[4][4] = {};
  const u16* Pb = probs + (size_t)((b * 16 + h) * 256) * 256;
  const int cc = lane & 15, kg = (lane >> 4) * 8;
#pragma unroll
  for (int kt = 0; kt < 8; ++kt) {
    bf16x8 a[4], v[4];
#pragma unroll
    for (int m = 0; m < 4; ++m)
      a[m] = *(const bf16x8*)(Pb + (size_t)(wave * 64 + m * 16 + cc) * 256 + kt * 32 + kg);
#pragma unroll
    for (int n = 0; n < 4; ++n) {
      int d = n * 16 + cc;
      int kk = kt * 32 + kg;
      int byt = (d * 512 + kk * 2) ^ ((d & 7) << 4);
      v[n] = *(const bf16x8*)((const char*)Vs + byt);
    }
#pragma unroll
    for (int m = 0; m < 4; ++m)
#pragma unroll
      for (int n = 0; n < 4; ++n)
        acc[m][n] = mfma16(a[m], v[n], acc[m][n]);
  }

  const int r0 = (lane >> 4) * 4;
#pragma unroll
  for (int m = 0; m < 4; ++m) {
    const int q = wave * 64 + m * 16 + r0;
#pragma unroll
    for (int n = 0; n < 4; ++n) {
      const int col = h * 64 + n * 16 + cc;
#pragma unroll
      for (int r = 0; r < 4; ++r)
        ctx[(size_t)(b * 256 + q + r) * 1024 + col] = f2bf(acc[m][n][r]);
    }
  }
}

// ---------------------------------------------------------------------------
extern "C" void kernel_launch(void* const* d_in, const int* in_sizes, int n_in,
                              void* d_out, int out_size, void* d_ws, size_t ws_size,
                              hipStream_t stream) {
  const float* X      = (const float*)d_in[0];
  const float* W_qkv  = (const float*)d_in[1];
  const float* b_qkv  = (const float*)d_in[2];
  const float* W_proj = (const float*)d_in[3];
  const float* b_proj = (const float*)d_in[4];
  const float* g1     = (const float*)d_in[5];
  const float* beta1  = (const float*)d_in[6];
  const float* g2     = (const float*)d_in[7];
  const float* beta2  = (const float*)d_in[8];
  const float* W_ff1  = (const float*)d_in[9];
  const float* b_ff1  = (const float*)d_in[10];
  const float* W_ff2  = (const float*)d_in[11];
  const float* b_ff2  = (const float*)d_in[12];

  float* Xout = (float*)d_out;                 // [8192][1024]
  float* Aout = (float*)d_out + 8388608;       // [32][256][256]

  char* ws = (char*)d_ws;
  const size_t MB = 1u << 20;
  u16* xn    = (u16*)(ws + 0);          // 16MB: Xn, then ctx, then X1n
  u16* wqkv  = (u16*)(ws + 16 * MB);    // 6MB [3072][1024]
  u16* wproj = (u16*)(ws + 22 * MB);    // 2MB [1024][1024]
  u16* wff1  = (u16*)(ws + 24 * MB);    // 8MB [4096][1024]
  u16* wff2  = (u16*)(ws + 32 * MB);    // 8MB [1024][4096]
  u16* qkv   = (u16*)(ws + 40 * MB);    // 48MB [8192][3072]
  u16* probs = (u16*)(ws + 88 * MB);    // 64MB [32][16][256][256]; later h
  u16* hbuf  = probs;                   // 64MB [8192][4096]
  float* x1  = (float*)(ws + 152 * MB); // 32MB [8192][1024]  (total 184MB)
  u16* ctx   = xn;                      // reuse region 0 after QKV GEMM
  u16* x1n   = xn;                      // reuse region 0 after proj GEMM

  const dim3 tb(32, 8);
  transpose_cast<<<dim3(96, 32),  tb, 0, stream>>>(W_qkv,  wqkv, 1024, 3072);
  transpose_cast<<<dim3(32, 32),  tb, 0, stream>>>(W_proj, wproj, 1024, 1024);
  transpose_cast<<<dim3(128, 32), tb, 0, stream>>>(W_ff1,  wff1, 1024, 4096);
  transpose_cast<<<dim3(32, 128), tb, 0, stream>>>(W_ff2,  wff2, 4096, 1024);

  layernorm_bf16<<<8192, 256, 0, stream>>>(X, g1, beta1, xn);

  // QKV: gemm_sb (measured best for large-N). Grid 64x24 = 1536 blocks.
  gemm_sb<0><<<1536, 256, 0, stream>>>(xn, wqkv, b_qkv, nullptr, nullptr, qkv,
                                       8192, 3072, 1024);

  attn_scores<<<dim3(4, 16, 32), 256, 0, stream>>>(qkv, probs);
  amean<<<8192, 256, 0, stream>>>(probs, Aout);
  attn_pv<<<dim3(16, 32), 256, 0, stream>>>(qkv, probs, ctx);

  // proj + residual: gemm_128 ring-2 (measured best for these). 512 blocks.
  gemm_128<1><<<512, 256, 0, stream>>>(ctx, wproj, b_proj, X, x1, nullptr,
                                       8192, 1024, 1024);

  layernorm_bf16<<<8192, 256, 0, stream>>>(x1, g2, beta2, x1n);

  // FF1 + GELU: gemm_sb. Grid 64x32 = 2048 blocks.
  gemm_sb<2><<<2048, 256, 0, stream>>>(x1n, wff1, b_ff1, nullptr, nullptr, hbuf,
                                       8192, 4096, 1024);

  // FF2 + residual: gemm_128 ring-2. 512 blocks.
  gemm_128<1><<<512, 256, 0, stream>>>(hbuf, wff2, b_ff2, x1, Xout, nullptr,
                                       8192, 1024, 4096);
}

// Round 16
// 332.282 us; speedup vs baseline: 1.1493x; 1.0121x over previous
//
#include <hip/hip_runtime.h>
#include <cstdint>
#include <cstddef>

typedef short bf16x8 __attribute__((ext_vector_type(8)));
typedef float f32x4 __attribute__((ext_vector_type(4)));
typedef unsigned short u16;
typedef u16 u16x8 __attribute__((ext_vector_type(8)));
typedef u16 u16x4 __attribute__((ext_vector_type(4)));

#define GLD16(gptr, lptr)                                                            \
  __builtin_amdgcn_global_load_lds((const __attribute__((address_space(1))) void*)(gptr), \
                                   (__attribute__((address_space(3))) void*)(lptr), 16, 0, 0)

__device__ __forceinline__ u16 f2bf(float f) {
  union { float f; unsigned u; } v; v.f = f;
  unsigned r = v.u + 0x7FFF + ((v.u >> 16) & 1);
  return (u16)(r >> 16);
}
__device__ __forceinline__ float bf2f(u16 h) {
  union { unsigned u; float f; } v; v.u = ((unsigned)h) << 16;
  return v.f;
}

__device__ __forceinline__ f32x4 mfma16(bf16x8 a, bf16x8 b, f32x4 c) {
  return __builtin_amdgcn_mfma_f32_16x16x32_bf16(a, b, c, 0, 0, 0);
}

// read 8 contiguous bf16 from a [rows][64] bf16 LDS tile with XOR swizzle
__device__ __forceinline__ bf16x8 lds_read_sw64(const u16* base, int row, int col) {
  int byt = row * 128 + col * 2;
  byt ^= (row & 7) << 4;
  return *(const bf16x8*)((const char*)base + byt);
}

// ---------------------------------------------------------------------------
// Weight transpose + cast: out[c][r] = bf16(in[r][c]); R,C multiples of 32
// ---------------------------------------------------------------------------
__global__ __launch_bounds__(256) void transpose_cast(const float* __restrict__ in,
                                                      u16* __restrict__ out, int R, int C) {
  __shared__ float tile[32][33];
  const int tx = threadIdx.x, ty = threadIdx.y;
  const int c0 = blockIdx.x * 32, r0 = blockIdx.y * 32;
#pragma unroll
  for (int i = 0; i < 32; i += 8)
    tile[ty + i][tx] = in[(size_t)(r0 + ty + i) * C + c0 + tx];
  __syncthreads();
#pragma unroll
  for (int i = 0; i < 32; i += 8)
    out[(size_t)(c0 + ty + i) * R + r0 + tx] = f2bf(tile[tx][ty + i]);
}

// ---------------------------------------------------------------------------
// LayerNorm (D=1024): fp32 in -> bf16 out
// ---------------------------------------------------------------------------
__global__ __launch_bounds__(256) void layernorm_bf16(const float* __restrict__ X,
                                                      const float* __restrict__ g,
                                                      const float* __restrict__ be,
                                                      u16* __restrict__ out) {
  const int row = blockIdx.x, t = threadIdx.x;
  const int lane = t & 63, wave = t >> 6;
  const float* x = X + (size_t)row * 1024;
  __shared__ float part[4];
  float v[4]; float s = 0.f;
#pragma unroll
  for (int i = 0; i < 4; ++i) { v[i] = x[t + i * 256]; s += v[i]; }
#pragma unroll
  for (int o = 32; o >= 1; o >>= 1) s += __shfl_xor(s, o);
  if (lane == 0) part[wave] = s;
  __syncthreads();
  const float mu = (part[0] + part[1] + part[2] + part[3]) * (1.f / 1024.f);
  float d2 = 0.f;
#pragma unroll
  for (int i = 0; i < 4; ++i) { float d = v[i] - mu; d2 += d * d; }
#pragma unroll
  for (int o = 32; o >= 1; o >>= 1) d2 += __shfl_xor(d2, o);
  __syncthreads();
  if (lane == 0) part[wave] = d2;
  __syncthreads();
  const float var = (part[0] + part[1] + part[2] + part[3]) * (1.f / 1024.f);
  const float rstd = rsqrtf(var + 1e-5f);
#pragma unroll
  for (int i = 0; i < 4; ++i) {
    const int c = t + i * 256;
    out[(size_t)row * 1024 + c] = f2bf((v[i] - mu) * rstd * g[c] + be[c]);
  }
}

// ---------------------------------------------------------------------------
// LayerNorm (D=1024): bf16 in -> bf16 out (u16x4 vector loads, 8B/lane)
// ---------------------------------------------------------------------------
__global__ __launch_bounds__(256) void layernorm_bb(const u16* __restrict__ Xb,
                                                    const float* __restrict__ g,
                                                    const float* __restrict__ be,
                                                    u16* __restrict__ out) {
  const int row = blockIdx.x, t = threadIdx.x;
  const int lane = t & 63, wave = t >> 6;
  __shared__ float part[4];
  const u16x4 xv = *(const u16x4*)(Xb + (size_t)row * 1024 + t * 4);
  float v[4]; float s = 0.f;
#pragma unroll
  for (int i = 0; i < 4; ++i) { v[i] = bf2f(xv[i]); s += v[i]; }
#pragma unroll
  for (int o = 32; o >= 1; o >>= 1) s += __shfl_xor(s, o);
  if (lane == 0) part[wave] = s;
  __syncthreads();
  const float mu = (part[0] + part[1] + part[2] + part[3]) * (1.f / 1024.f);
  float d2 = 0.f;
#pragma unroll
  for (int i = 0; i < 4; ++i) { float d = v[i] - mu; d2 += d * d; }
#pragma unroll
  for (int o = 32; o >= 1; o >>= 1) d2 += __shfl_xor(d2, o);
  __syncthreads();
  if (lane == 0) part[wave] = d2;
  __syncthreads();
  const float var = (part[0] + part[1] + part[2] + part[3]) * (1.f / 1024.f);
  const float rstd = rsqrtf(var + 1e-5f);
#pragma unroll
  for (int i = 0; i < 4; ++i) {
    const int c = t * 4 + i;
    out[(size_t)row * 1024 + c] = f2bf((v[i] - mu) * rstd * g[c] + be[c]);
  }
}

// ---------------------------------------------------------------------------
// m97-replica 128x128 bf16 MFMA GEMM (r11, measured ~830 TF): single 32KB
// LDS buffer, full drain per K-step, ~2.7 blocks/CU cross-block overlap.
// EPI 0: bf16 out; EPI 2: bf16 gelu(acc+bias)
// ---------------------------------------------------------------------------
template <int EPI>
__global__ __launch_bounds__(256, 2) void gemm_sb(const u16* __restrict__ A,
                                                  const u16* __restrict__ Bt,
                                                  const float* __restrict__ bias,
                                                  u16* __restrict__ outb,
                                                  int M, int N, int K) {
  constexpr int ABYT = 128 * 128;   // 16KB per operand
  __shared__ __attribute__((aligned(16))) char lds[2 * ABYT];  // 32KB

  const int t = threadIdx.x, lane = t & 63, wave = t >> 6;
  const int wm = wave >> 1, wn = wave & 1;
  const int l15 = lane & 15, l16 = lane >> 4;

  const int xcd = (int)blockIdx.x & 7, q = (int)blockIdx.x >> 3;
  const int j = q & 63, gq = q >> 6;
  const int g = gq * 8 + xcd;
  const int NGN = N >> 10;
  const int gm = g / NGN, gn = g % NGN;
  const int bm = (gm * 8 + (j >> 3)) * 128;
  const int bn = (gn * 8 + (j & 7)) * 128;

  const u16* aptr[4];
  const u16* bptr[4];
#pragma unroll
  for (int c = 0; c < 4; ++c) {
    int Lb = c * 4096 + t * 16;
    int x = (Lb ^ ((Lb >> 3) & 0x70)) >> 1;
    aptr[c] = A + (size_t)(bm + (x >> 6)) * K + (x & 63);
    bptr[c] = Bt + (size_t)(bn + (x >> 6)) * K + (x & 63);
  }

  auto stage = [&](int p) {
    const int ko = p * 64;
    char* ab = lds + t * 16;
    char* bb = lds + ABYT + t * 16;
#pragma unroll
    for (int c = 0; c < 4; ++c) GLD16(aptr[c] + ko, ab + c * 4096);
#pragma unroll
    for (int c = 0; c < 4; ++c) GLD16(bptr[c] + ko, bb + c * 4096);
  };

  const int co0 = l16 * 16, co1 = 64 + l16 * 16;
  f32x4 acc[4][4] = {};
  const int nkt = K >> 6;

#pragma unroll 1
  for (int kt = 0; kt < nkt; ++kt) {
    __syncthreads();
    stage(kt);
    __syncthreads();

    const char* ab = lds;
    const char* bb = lds + ABYT;
#pragma unroll
    for (int ks = 0; ks < 2; ++ks) {
      const int co = ks ? co1 : co0;
      bf16x8 a[4], b[4];
#pragma unroll
      for (int m = 0; m < 4; ++m) {
        const int r = wm * 64 + m * 16 + l15;
        a[m] = *(const bf16x8*)(ab + r * 128 + (co ^ ((r & 7) << 4)));
      }
#pragma unroll
      for (int n = 0; n < 4; ++n) {
        const int r = wn * 64 + n * 16 + l15;
        b[n] = *(const bf16x8*)(bb + r * 128 + (co ^ ((r & 7) << 4)));
      }
#pragma unroll
      for (int m = 0; m < 4; ++m)
#pragma unroll
        for (int n = 0; n < 4; ++n)
          acc[m][n] = mfma16(a[m], b[n], acc[m][n]);
    }
  }

  const int r0 = l16 * 4;
#pragma unroll
  for (int m = 0; m < 4; ++m) {
#pragma unroll
    for (int n = 0; n < 4; ++n) {
      const int col = bn + wn * 64 + n * 16 + l15;
      const float bv = bias[col];
#pragma unroll
      for (int r = 0; r < 4; ++r) {
        const int row = bm + wm * 64 + m * 16 + r0 + r;
        const float v = acc[m][n][r] + bv;
        const size_t o = (size_t)row * N + col;
        if (EPI == 0) {
          outb[o] = f2bf(v);
        } else {
          const float u = 0.7978845608f * (v + 0.044715f * v * v * v);
          const float e = __expf(2.f * u);
          const float th = 1.f - 2.f / (1.f + e);
          outb[o] = f2bf(0.5f * v * (1.f + th));
        }
      }
    }
  }
}

// ---------------------------------------------------------------------------
// Ring-2 double-buffer 128x128 GEMM (r10): used for proj and FF2.
// EPI 3: f32 out = bf16res + acc + bias;  EPI 4: bf16 out = f32res + acc + bias
// ---------------------------------------------------------------------------
template <int EPI>
__global__ __launch_bounds__(256, 2) void gemm_128(const u16* __restrict__ A,
                                                   const u16* __restrict__ Bt,
                                                   const float* __restrict__ bias,
                                                   const float* __restrict__ resf,
                                                   const u16* __restrict__ resb,
                                                   float* __restrict__ outf,
                                                   u16* __restrict__ outb,
                                                   int M, int N, int K) {
  constexpr int ABYT = 128 * 128;   // 16KB per K-tile per operand
  __shared__ __attribute__((aligned(16))) char lds[4 * ABYT];  // 64KB

  const int t = threadIdx.x, lane = t & 63, wave = t >> 6;
  const int wm = wave >> 1, wn = wave & 1;
  const int l15 = lane & 15, l16 = lane >> 4;

  const int xcd = (int)blockIdx.x & 7, q = (int)blockIdx.x >> 3;
  const int j = q & 63, gq = q >> 6;
  const int g = gq * 8 + xcd;
  const int NGN = N >> 10;
  const int gm = g / NGN, gn = g % NGN;
  const int bm = (gm * 8 + (j >> 3)) * 128;
  const int bn = (gn * 8 + (j & 7)) * 128;

  const u16* aptr[4];
  const u16* bptr[4];
#pragma unroll
  for (int c = 0; c < 4; ++c) {
    int Lb = c * 4096 + t * 16;
    int x = (Lb ^ ((Lb >> 3) & 0x70)) >> 1;
    aptr[c] = A + (size_t)(bm + (x >> 6)) * K + (x & 63);
    bptr[c] = Bt + (size_t)(bn + (x >> 6)) * K + (x & 63);
  }

  auto stage = [&](int p) {
    const int ko = p * 64;
    const int s = p & 1;
    char* ab = lds + s * ABYT + t * 16;
    char* bb = lds + 2 * ABYT + s * ABYT + t * 16;
#pragma unroll
    for (int c = 0; c < 4; ++c) GLD16(aptr[c] + ko, ab + c * 4096);
#pragma unroll
    for (int c = 0; c < 4; ++c) GLD16(bptr[c] + ko, bb + c * 4096);
  };
  stage(0);

  const int co0 = l16 * 16, co1 = 64 + l16 * 16;
  f32x4 acc[4][4] = {};
  const int nkt = K >> 6;

#pragma unroll 1
  for (int kt = 0; kt < nkt; ++kt) {
    asm volatile("s_waitcnt vmcnt(0)" ::: "memory");
    asm volatile("s_barrier" ::: "memory");
    if (kt + 1 < nkt) stage(kt + 1);

    const int s = kt & 1;
    const char* ab = lds + s * ABYT;
    const char* bb = lds + 2 * ABYT + s * ABYT;
#pragma unroll
    for (int ks = 0; ks < 2; ++ks) {
      const int co = ks ? co1 : co0;
      bf16x8 a[4], b[4];
#pragma unroll
      for (int m = 0; m < 4; ++m) {
        const int r = wm * 64 + m * 16 + l15;
        a[m] = *(const bf16x8*)(ab + r * 128 + (co ^ ((r & 7) << 4)));
      }
#pragma unroll
      for (int n = 0; n < 4; ++n) {
        const int r = wn * 64 + n * 16 + l15;
        b[n] = *(const bf16x8*)(bb + r * 128 + (co ^ ((r & 7) << 4)));
      }
      __builtin_amdgcn_s_setprio(1);
#pragma unroll
      for (int m = 0; m < 4; ++m)
#pragma unroll
        for (int n = 0; n < 4; ++n)
          acc[m][n] = mfma16(a[m], b[n], acc[m][n]);
      __builtin_amdgcn_s_setprio(0);
    }
  }

  const int r0 = l16 * 4;
#pragma unroll
  for (int m = 0; m < 4; ++m) {
#pragma unroll
    for (int n = 0; n < 4; ++n) {
      const int col = bn + wn * 64 + n * 16 + l15;
      const float bv = bias[col];
#pragma unroll
      for (int r = 0; r < 4; ++r) {
        const int row = bm + wm * 64 + m * 16 + r0 + r;
        const float v = acc[m][n][r] + bv;
        const size_t o = (size_t)row * N + col;
        if (EPI == 3) {
          outf[o] = bf2f(resb[o]) + v;        // FF2: f32 out = bf16 res + acc
        } else {
          outb[o] = f2bf(resf[o] + v);        // proj: bf16 out = f32 res + acc
        }
      }
    }
  }
}

// ---------------------------------------------------------------------------
// Attention scores + softmax -> probs (bf16). grid(4 qblk, 16 h, 32 b), 256 thr
// probs layout: [b][h][q][k] = [((b*16+h)*256+q)*256+k]
// ---------------------------------------------------------------------------
__global__ __launch_bounds__(256) void attn_scores(const u16* __restrict__ qkv,
                                                   u16* __restrict__ probs) {
  __shared__ u16 Ks[256 * 64];
  __shared__ u16 Qs[64 * 64];
  const int t = threadIdx.x, lane = t & 63, wave = t >> 6;
  const int qb = blockIdx.x * 64, h = blockIdx.y, b = blockIdx.z;
  const size_t row0 = (size_t)b * 256 * 3072;

#pragma unroll
  for (int is = 0; is < 8; ++is) {
    int L = (is * 2048 + t * 8) * 2;
    int x = (L ^ ((L >> 3) & 0x70)) >> 1;
    int kk = x >> 6, d = x & 63;
    const u16* gp = qkv + row0 + (size_t)kk * 3072 + 1024 + h * 64 + d;
    GLD16(gp, (char*)Ks + is * 4096 + wave * 1024);
  }
#pragma unroll
  for (int is = 0; is < 2; ++is) {
    int L = (is * 2048 + t * 8) * 2;
    int x = (L ^ ((L >> 3) & 0x70)) >> 1;
    int q = x >> 6, d = x & 63;
    const u16* gp = qkv + row0 + (size_t)(qb + q) * 3072 + h * 64 + d;
    GLD16(gp, (char*)Qs + is * 4096 + wave * 1024);
  }
  __syncthreads();

  f32x4 acc[16] = {};
  bf16x8 aq[2];
#pragma unroll
  for (int ks = 0; ks < 2; ++ks)
    aq[ks] = lds_read_sw64(Qs, wave * 16 + (lane & 15), ks * 32 + (lane >> 4) * 8);
#pragma unroll
  for (int nf = 0; nf < 16; ++nf) {
#pragma unroll
    for (int ks = 0; ks < 2; ++ks) {
      bf16x8 bk = lds_read_sw64(Ks, nf * 16 + (lane & 15), ks * 32 + (lane >> 4) * 8);
      acc[nf] = mfma16(aq[ks], bk, acc[nf]);
    }
  }

  const int r0 = (lane >> 4) * 4, cc = lane & 15;
  const float sc = 0.125f;
#pragma unroll
  for (int r = 0; r < 4; ++r) {
    float mx = -1e30f;
#pragma unroll
    for (int nf = 0; nf < 16; ++nf) mx = fmaxf(mx, acc[nf][r]);
#pragma unroll
    for (int o = 8; o >= 1; o >>= 1) mx = fmaxf(mx, __shfl_xor(mx, o));
    float s = 0.f;
#pragma unroll
    for (int nf = 0; nf < 16; ++nf) {
      float e = __expf((acc[nf][r] - mx) * sc);
      acc[nf][r] = e; s += e;
    }
#pragma unroll
    for (int o = 8; o >= 1; o >>= 1) s += __shfl_xor(s, o);
    const float rinv = 1.f / s;
    const int qrow = qb + wave * 16 + r0 + r;
    u16* prow = probs + (size_t)((b * 16 + h) * 256 + qrow) * 256;
#pragma unroll
    for (int nf = 0; nf < 16; ++nf)
      prow[nf * 16 + cc] = f2bf(acc[nf][r] * rinv);
  }
}

// ---------------------------------------------------------------------------
// A = mean over heads of probs. grid(8192=b*256+q), 256 thr
// ---------------------------------------------------------------------------
__global__ __launch_bounds__(256) void amean(const u16* __restrict__ probs,
                                             float* __restrict__ A) {
  const int bq = blockIdx.x;
  const int b = bq >> 8, q = bq & 255;
  const int t = threadIdx.x;
  float s = 0.f;
#pragma unroll
  for (int h = 0; h < 16; ++h)
    s += bf2f(probs[(size_t)((b * 16 + h) * 256 + q) * 256 + t]);
  A[(size_t)bq * 256 + t] = s * (1.f / 16.f);
}

// ---------------------------------------------------------------------------
// PV: ctx[b,:,h*64:+64] = probs[b,h] @ V[b,h]. grid(16 h, 32 b), 256 thr
// ---------------------------------------------------------------------------
__global__ __launch_bounds__(256) void attn_pv(const u16* __restrict__ qkv,
                                               const u16* __restrict__ probs,
                                               u16* __restrict__ ctx) {
  __shared__ u16 Vs[64 * 256];
  const int t = threadIdx.x, lane = t & 63, wave = t >> 6;
  const int h = blockIdx.x, b = blockIdx.y;

#pragma unroll
  for (int p = 0; p < 8; ++p) {
    int idx = p * 2048 + t * 8;
    int kk = idx >> 6, d0 = idx & 63;
    u16x8 vv = *(const u16x8*)(qkv + (size_t)(b * 256 + kk) * 3072 + 2048 + h * 64 + d0);
#pragma unroll
    for (int j = 0; j < 8; ++j) {
      int d = d0 + j;
      int byt = (d * 512 + kk * 2) ^ ((d & 7) << 4);
      *(u16*)((char*)Vs + byt) = vv[j];
    }
  }
  __syncthreads();

  f32x4 acc[4][4] = {};
  const u16* Pb = probs + (size_t)((b * 16 + h) * 256) * 256;
  const int cc = lane & 15, kg = (lane >> 4) * 8;
#pragma unroll
  for (int kt = 0; kt < 8; ++kt) {
    bf16x8 a[4], v[4];
#pragma unroll
    for (int m = 0; m < 4; ++m)
      a[m] = *(const bf16x8*)(Pb + (size_t)(wave * 64 + m * 16 + cc) * 256 + kt * 32 + kg);
#pragma unroll
    for (int n = 0; n < 4; ++n) {
      int d = n * 16 + cc;
      int kk = kt * 32 + kg;
      int byt = (d * 512 + kk * 2) ^ ((d & 7) << 4);
      v[n] = *(const bf16x8*)((const char*)Vs + byt);
    }
#pragma unroll
    for (int m = 0; m < 4; ++m)
#pragma unroll
      for (int n = 0; n < 4; ++n)
        acc[m][n] = mfma16(a[m], v[n], acc[m][n]);
  }

  const int r0 = (lane >> 4) * 4;
#pragma unroll
  for (int m = 0; m < 4; ++m) {
    const int q = wave * 64 + m * 16 + r0;
#pragma unroll
    for (int n = 0; n < 4; ++n) {
      const int col = h * 64 + n * 16 + cc;
#pragma unroll
      for (int r = 0; r < 4; ++r)
        ctx[(size_t)(b * 256 + q + r) * 1024 + col] = f2bf(acc[m][n][r]);
    }
  }
}

// ---------------------------------------------------------------------------
extern "C" void kernel_launch(void* const* d_in, const int* in_sizes, int n_in,
                              void* d_out, int out_size, void* d_ws, size_t ws_size,
                              hipStream_t stream) {
  const float* X      = (const float*)d_in[0];
  const float* W_qkv  = (const float*)d_in[1];
  const float* b_qkv  = (const float*)d_in[2];
  const float* W_proj = (const float*)d_in[3];
  const float* b_proj = (const float*)d_in[4];
  const float* g1     = (const float*)d_in[5];
  const float* beta1  = (const float*)d_in[6];
  const float* g2     = (const float*)d_in[7];
  const float* beta2  = (const float*)d_in[8];
  const float* W_ff1  = (const float*)d_in[9];
  const float* b_ff1  = (const float*)d_in[10];
  const float* W_ff2  = (const float*)d_in[11];
  const float* b_ff2  = (const float*)d_in[12];

  float* Xout = (float*)d_out;                 // [8192][1024]
  float* Aout = (float*)d_out + 8388608;       // [32][256][256]

  char* ws = (char*)d_ws;
  const size_t MB = 1u << 20;
  u16* xn    = (u16*)(ws + 0);          // 16MB: Xn, then ctx, then X1n
  u16* wqkv  = (u16*)(ws + 16 * MB);    // 6MB [3072][1024]
  u16* wproj = (u16*)(ws + 22 * MB);    // 2MB [1024][1024]
  u16* wff1  = (u16*)(ws + 24 * MB);    // 8MB [4096][1024]
  u16* wff2  = (u16*)(ws + 32 * MB);    // 8MB [1024][4096]
  u16* qkv   = (u16*)(ws + 40 * MB);    // 48MB [8192][3072]
  u16* probs = (u16*)(ws + 88 * MB);    // 64MB [32][16][256][256]; later h
  u16* hbuf  = probs;                   // 64MB [8192][4096]
  u16* x1b   = (u16*)(ws + 152 * MB);   // 16MB [8192][1024] bf16
  u16* ctx   = xn;                      // reuse region 0 after QKV GEMM
  u16* x1n   = xn;                      // reuse region 0 after proj GEMM

  const dim3 tb(32, 8);
  transpose_cast<<<dim3(96, 32),  tb, 0, stream>>>(W_qkv,  wqkv, 1024, 3072);
  transpose_cast<<<dim3(32, 32),  tb, 0, stream>>>(W_proj, wproj, 1024, 1024);
  transpose_cast<<<dim3(128, 32), tb, 0, stream>>>(W_ff1,  wff1, 1024, 4096);
  transpose_cast<<<dim3(32, 128), tb, 0, stream>>>(W_ff2,  wff2, 4096, 1024);

  layernorm_bf16<<<8192, 256, 0, stream>>>(X, g1, beta1, xn);

  // QKV: gemm_sb. Grid 64x24 = 1536 blocks.
  gemm_sb<0><<<1536, 256, 0, stream>>>(xn, wqkv, b_qkv, qkv, 8192, 3072, 1024);

  attn_scores<<<dim3(4, 16, 32), 256, 0, stream>>>(qkv, probs);
  amean<<<8192, 256, 0, stream>>>(probs, Aout);
  attn_pv<<<dim3(16, 32), 256, 0, stream>>>(qkv, probs, ctx);

  // proj + residual: x1b (bf16) = X + ctx@W_proj + b. 512 blocks.
  gemm_128<4><<<512, 256, 0, stream>>>(ctx, wproj, b_proj, X, nullptr, nullptr, x1b,
                                       8192, 1024, 1024);

  layernorm_bb<<<8192, 256, 0, stream>>>(x1b, g2, beta2, x1n);

  // FF1 + GELU: gemm_sb. Grid 64x32 = 2048 blocks.
  gemm_sb<2><<<2048, 256, 0, stream>>>(x1n, wff1, b_ff1, hbuf, 8192, 4096, 1024);

  // FF2 + residual: Xout (f32) = x1b + h@W_ff2 + b. 512 blocks.
  gemm_128<3><<<512, 256, 0, stream>>>(hbuf, wff2, b_ff2, nullptr, x1b, Xout, nullptr,
                                       8192, 1024, 4096);
}